// Round 9
// baseline (975.090 us; speedup 1.0000x reference)
//
#include <hip/hip_runtime.h>

// ---------------------------------------------------------------------------
// Model_16690242912472: Reformer-style forecaster.
// B=8, L=2048, D_MODEL=512, H=8, DH=64, DFF=2048, 2 layers,
// LSH attn: 4 hashes, 32 buckets, bucket_size 64 -> 128 chunks of 64.
// R9: gemm_k -> BK=32 body (chain bit-verified in R7's passing run);
// lsh_attn: Ps aliased onto Ks (+1 barrier) 53->36KB LDS, launch_bounds(256,4)
// caps VGPR 136->128 => 12->16 waves/CU. All numerics frozen.
// ---------------------------------------------------------------------------

#define BATCH 8
#define SEQL 2048
#define DM 512
#define NH 8
#define DH 64
#define DFF 2048
#define NHASH 4
#define NBUCK 32
#define NCHUNK 128   // NHASH*NBUCK
#define CS 64        // chunk size
#define ROWS (BATCH*SEQL)      // 16384
#define BHN (BATCH*NH)         // 64
#define SORTN (NHASH*SEQL)     // 8192
#define SELF_VAL -5e4f

typedef __attribute__((ext_vector_type(4))) float f32x4;
typedef __attribute__((ext_vector_type(8))) short short8;

__device__ __forceinline__ float bfu2f(unsigned int u16) {
    return __uint_as_float(u16 << 16);
}
__device__ __forceinline__ unsigned short f2bfu(float f) {
    unsigned int x = __float_as_uint(f);
    x += 0x7fffu + ((x >> 16) & 1u);   // RNE (inputs finite)
    return (unsigned short)(x >> 16);
}

__device__ __forceinline__ void gld16(const void* g, void* l) {
    __builtin_amdgcn_global_load_lds(
        (const __attribute__((address_space(1))) unsigned int*)g,
        (__attribute__((address_space(3))) unsigned int*)l, 16, 0, 0);
}

// ------------------------- embedding (frozen) --------------------------------
__device__ __forceinline__ float getx(const float* xe, const float* xd, int b, int lm, int c) {
    return (lm < 1536) ? xe[((size_t)b * 1536 + lm) * 7 + c]
                       : xd[((size_t)b * 1024 + (lm - 1024)) * 7 + c];
}

__global__ __launch_bounds__(512) void embed_k(
    const float* __restrict__ x_enc, const float* __restrict__ x_me,
    const float* __restrict__ x_dec, const float* __restrict__ x_md,
    const float* __restrict__ cw, const float* __restrict__ tw,
    float* __restrict__ h, unsigned short* __restrict__ hb)
{
    const int row = blockIdx.x;            // 0..16383
    const int b = row >> 11, l = row & 2047;
    const int d = threadIdx.x;             // 0..511
    __shared__ float xs[21];
    __shared__ float xms[4];
    if (d < 21) {
        const int k = d / 7, c = d % 7;
        const int lm = (l + k + 2047) & 2047;   // l-1+k circular
        xs[d] = getx(x_enc, x_dec, b, lm, c);
    } else if (d < 25) {
        const int m = d - 21;
        xms[m] = (l < 1536) ? x_me[((size_t)b * 1536 + l) * 4 + m]
                            : x_md[((size_t)b * 1024 + (l - 1024)) * 4 + m];
    }
    __syncthreads();
    float tok = 0.f;
    #pragma unroll
    for (int kc = 0; kc < 21; ++kc) tok = fmaf(xs[kc], cw[kc * 512 + d], tok);
    float tm = 0.f;
    #pragma unroll
    for (int m = 0; m < 4; ++m) tm = fmaf(xms[m], tw[m * 512 + d], tm);
    const int pair = d & ~1;
    const float freq = expf((float)pair * (-9.210340371976184f / 512.f)); // ln(1e4)
    const float ang = (float)l * freq;
    const float pe = (d & 1) ? cosf(ang) : sinf(ang);
    const float val = tok + pe + tm;
    h[(size_t)row * 512 + d] = val;
    hb[(size_t)row * 512 + d] = f2bfu(val);
}

// ------------------------- fp32 GEMM (qk/hash path) -------------------------
// 128x64 tile, BK=32, reg prefetch. Per-output accumulation: one fmaf per k,
// ascending k -> bit-identical chain (verified in R7's passing run).
__global__ __launch_bounds__(256) void gemm_k(
    const float* __restrict__ A, const float* __restrict__ B,
    float* __restrict__ C, int M, int N, int K)
{
    __shared__ float As[32][132];
    __shared__ float Bs[32][64];
    const int tid = threadIdx.x;
    const int bm = blockIdx.x * 128, bn = blockIdx.y * 64;
    const int ty = tid >> 4, tx = tid & 15;
    const int ar = tid >> 1, ac = (tid & 1) * 16;   // A: 128 rows x 32 k
    const int br = tid >> 3, bc = (tid & 7) * 8;    // B: 32 rows x 64 n
    float acc[8][4] = {};
    const float* Ap = A + (size_t)(bm + ar) * K + ac;
    const float* Bp = B + (size_t)br * N + bn + bc;
    float4 av0 = *reinterpret_cast<const float4*>(Ap);
    float4 av1 = *reinterpret_cast<const float4*>(Ap + 4);
    float4 av2 = *reinterpret_cast<const float4*>(Ap + 8);
    float4 av3 = *reinterpret_cast<const float4*>(Ap + 12);
    float4 bv0 = *reinterpret_cast<const float4*>(Bp);
    float4 bv1 = *reinterpret_cast<const float4*>(Bp + 4);
    for (int k0 = 0; k0 < K; k0 += 32) {
        As[ac + 0][ar] = av0.x; As[ac + 1][ar] = av0.y;
        As[ac + 2][ar] = av0.z; As[ac + 3][ar] = av0.w;
        As[ac + 4][ar] = av1.x; As[ac + 5][ar] = av1.y;
        As[ac + 6][ar] = av1.z; As[ac + 7][ar] = av1.w;
        As[ac + 8][ar] = av2.x; As[ac + 9][ar] = av2.y;
        As[ac + 10][ar] = av2.z; As[ac + 11][ar] = av2.w;
        As[ac + 12][ar] = av3.x; As[ac + 13][ar] = av3.y;
        As[ac + 14][ar] = av3.z; As[ac + 15][ar] = av3.w;
        *reinterpret_cast<float4*>(&Bs[br][bc])     = bv0;
        *reinterpret_cast<float4*>(&Bs[br][bc + 4]) = bv1;
        __syncthreads();
        if (k0 + 32 < K) {
            av0 = *reinterpret_cast<const float4*>(Ap + k0 + 32);
            av1 = *reinterpret_cast<const float4*>(Ap + k0 + 36);
            av2 = *reinterpret_cast<const float4*>(Ap + k0 + 40);
            av3 = *reinterpret_cast<const float4*>(Ap + k0 + 44);
            bv0 = *reinterpret_cast<const float4*>(Bp + (size_t)(k0 + 32) * N);
            bv1 = *reinterpret_cast<const float4*>(Bp + (size_t)(k0 + 32) * N + 4);
        }
        #pragma unroll
        for (int k = 0; k < 32; ++k) {
            const float4 a0 = *reinterpret_cast<const float4*>(&As[k][ty * 8]);
            const float4 a1 = *reinterpret_cast<const float4*>(&As[k][ty * 8 + 4]);
            const float4 b0 = *reinterpret_cast<const float4*>(&Bs[k][tx * 4]);
            const float a[8] = {a0.x,a0.y,a0.z,a0.w,a1.x,a1.y,a1.z,a1.w};
            const float bb[4] = {b0.x,b0.y,b0.z,b0.w};
            #pragma unroll
            for (int i = 0; i < 8; ++i)
                #pragma unroll
                for (int j = 0; j < 4; ++j) acc[i][j] = fmaf(a[i], bb[j], acc[i][j]);
        }
        __syncthreads();
    }
    #pragma unroll
    for (int i = 0; i < 8; ++i) {
        const size_t cb = (size_t)(bm + ty * 8 + i) * N + bn + tx * 4;
        *reinterpret_cast<float4*>(C + cb) = make_float4(acc[i][0],acc[i][1],acc[i][2],acc[i][3]);
    }
}

// ------------------------- weight transpose-cast (z = layer) -----------------
__global__ __launch_bounds__(256) void tcast_k(
    const float* __restrict__ W, unsigned short* __restrict__ Wt, int K, int N)
{
    __shared__ float t[32][33];
    const size_t zo = (size_t)blockIdx.z * K * N;
    const int kb = blockIdx.x * 32, nb = blockIdx.y * 32;
    const int tx = threadIdx.x & 31, ty = threadIdx.x >> 5;
    #pragma unroll
    for (int i = ty; i < 32; i += 8)
        t[i][tx] = W[zo + (size_t)(kb + i) * N + nb + tx];
    __syncthreads();
    #pragma unroll
    for (int i = ty; i < 32; i += 8)
        Wt[zo + (size_t)(nb + i) * K + kb + tx] = f2bfu(t[tx][i]);
}

// ------------------------- bf16 MFMA GEMM (R6-verbatim) ----------------------
template<int OUT_BF, int ACT, int BIAS>
__global__ __launch_bounds__(256) void mgemm_k(
    const unsigned short* __restrict__ A,
    const unsigned short* __restrict__ Bt,
    const float* __restrict__ bias,
    void* __restrict__ Cv, int N, int K)
{
    __shared__ unsigned short As[128 * 32];
    __shared__ unsigned short Bs[128 * 32];
    const int tid = threadIdx.x;
    const int bm = blockIdx.x * 128, bn = blockIdx.y * 128;
    const int lane = tid & 63, w = tid >> 6;
    const int wr = (w >> 1) * 64, wc = (w & 1) * 64;
    const int fr = lane & 15, fq = lane >> 4;
    const int r0 = tid >> 2, c0 = (tid & 3) * 8;
    const unsigned short* Ag = A + (size_t)(bm + r0) * K + c0;
    const unsigned short* Bg = Bt + (size_t)(bn + r0) * K + c0;
    f32x4 acc[4][4];
    #pragma unroll
    for (int i = 0; i < 4; ++i)
        #pragma unroll
        for (int j = 0; j < 4; ++j) acc[i][j] = (f32x4){0.f, 0.f, 0.f, 0.f};
    for (int k0 = 0; k0 < K; k0 += 32) {
        gld16(Ag + k0,                   As + tid * 8);
        gld16(Ag + (size_t)64 * K + k0,  As + tid * 8 + 2048);
        gld16(Bg + k0,                   Bs + tid * 8);
        gld16(Bg + (size_t)64 * K + k0,  Bs + tid * 8 + 2048);
        __syncthreads();
        short8 af[4], bfr[4];
        #pragma unroll
        for (int mi = 0; mi < 4; ++mi)
            af[mi] = *reinterpret_cast<const short8*>(As + (wr + mi * 16 + fr) * 32 + fq * 8);
        #pragma unroll
        for (int ni = 0; ni < 4; ++ni)
            bfr[ni] = *reinterpret_cast<const short8*>(Bs + (wc + ni * 16 + fr) * 32 + fq * 8);
        #pragma unroll
        for (int mi = 0; mi < 4; ++mi)
            #pragma unroll
            for (int ni = 0; ni < 4; ++ni)
                acc[mi][ni] = __builtin_amdgcn_mfma_f32_16x16x32_bf16(
                    af[mi], bfr[ni], acc[mi][ni], 0, 0, 0);
        __syncthreads();
    }
    float bv[4];
    if (BIAS) {
        #pragma unroll
        for (int ni = 0; ni < 4; ++ni) bv[ni] = bias[bn + wc + ni * 16 + fr];
    }
    #pragma unroll
    for (int mi = 0; mi < 4; ++mi) {
        #pragma unroll
        for (int r = 0; r < 4; ++r) {
            const int row = bm + wr + mi * 16 + fq * 4 + r;
            #pragma unroll
            for (int ni = 0; ni < 4; ++ni) {
                float val = acc[mi][ni][r];
                if (BIAS) val += bv[ni];
                if (ACT) val = 0.5f * val * (1.0f + erff(val * 0.7071067811865475f));
                const size_t idx = (size_t)row * N + bn + wc + ni * 16 + fr;
                if (OUT_BF) ((unsigned short*)Cv)[idx] = f2bfu(val);
                else        ((float*)Cv)[idx] = val;
            }
        }
    }
}

// ------------------------- LSH hashing (frozen, R8-verbatim) -----------------
__global__ __launch_bounds__(256, 4) void hash_k(
    const float* __restrict__ qk, const float* __restrict__ rot,
    int* __restrict__ buckets)
{
    __shared__ float rs[16][68];   // [j][d], padded
    const int t = threadIdx.x;
    const int hh_blk = blockIdx.x >> 9;      // 512 blocks per hh
    for (int u = t; u < 1024; u += 256) {
        const int d = u >> 4, j = u & 15;    // rot layout: d*64 + hh*16 + j
        rs[j][d] = rot[d * 64 + hh_blk * 16 + j];
    }
    __syncthreads();
    const int gid = blockIdx.x * 256 + t;    // 0..524287 = (hh, bh, l)
    const int l = gid & 2047;
    const int bh = (gid >> 11) & 63;
    const int hh = gid >> 17;                // == hh_blk
    const int b = bh >> 3, head = bh & 7;
    const float* qrow = qk + (size_t)(b * 2048 + l) * 512 + head * 64;
    float q[64];
    #pragma unroll
    for (int d4 = 0; d4 < 16; ++d4) {
        const float4 qq = reinterpret_cast<const float4*>(qrow)[d4];
        q[d4*4+0]=qq.x; q[d4*4+1]=qq.y; q[d4*4+2]=qq.z; q[d4*4+3]=qq.w;
    }
    float bvp = -1e38f, bvn = -1e38f;
    int bip = 0, bin_ = 16;
    #pragma unroll
    for (int j = 0; j < 16; ++j) {
        float dot = 0.f;
        #pragma unroll
        for (int d = 0; d < 64; d += 4) {
            const float4 r = *reinterpret_cast<const float4*>(&rs[j][d]);
            dot += q[d]*r.x + q[d+1]*r.y + q[d+2]*r.z + q[d+3]*r.w;
        }
        if (dot  > bvp) { bvp = dot;  bip = j; }
        if (-dot > bvn) { bvn = -dot; bin_ = 16 + j; }
    }
    const int idx = (bvn > bvp) ? bin_ : bip;   // ties -> + block (lower idx)
    buckets[((size_t)bh << 13) + hh * 2048 + l] = hh * 32 + idx;
}

// ------------------------- stable counting sort (frozen) ---------------------
__global__ __launch_bounds__(256) void sort_k(
    const int* __restrict__ buckets, int* __restrict__ st_sorted, int* __restrict__ pos_of)
{
    const int bh = blockIdx.x >> 2, hh = blockIdx.x & 3;
    const int t = threadIdx.x;
    __shared__ unsigned short cnt[256][32];
    __shared__ int tot[32];
    __shared__ int startc[32];
    {
        uint4* p = reinterpret_cast<uint4*>(&cnt[t][0]);
        const uint4 z = {0,0,0,0};
        #pragma unroll
        for (int q = 0; q < 4; ++q) p[q] = z;
    }
    const size_t base = (size_t)bh * SORTN + hh * 2048;
    int myb[8];
    #pragma unroll
    for (int j = 0; j < 8; ++j) {
        const int i = t * 8 + j;
        const int g = buckets[base + i] - hh * 32;
        myb[j] = g;
        cnt[t][g]++;
    }
    __syncthreads();
    if (t < 32) {
        int run = 0;
        for (int tt = 0; tt < 256; ++tt) {
            const int x = cnt[tt][t];
            cnt[tt][t] = (unsigned short)run;
            run += x;
        }
        tot[t] = run;
    }
    __syncthreads();
    if (t == 0) {
        int s = 0;
        for (int g = 0; g < 32; ++g) { startc[g] = s; s += tot[g]; }
    }
    __syncthreads();
    #pragma unroll
    for (int j = 0; j < 8; ++j) {
        const int i = t * 8 + j;
        const int g = myb[j];
        const int rank = cnt[t][g]++;
        const int pos = hh * 2048 + startc[g] + rank;
        st_sorted[(size_t)bh * SORTN + pos] = i;   // i == l within this hash round
        pos_of[base + i] = pos;
    }
}

// ------------------------- MFMA chunked LSH attention ------------------------
// Ps aliased onto Ks (Ks dead after dots; extra barrier fences the overwrite).
// LDS 53->35.8KB, VGPR capped 128 => 16 waves/CU. Values/chains unchanged.
__global__ __launch_bounds__(256, 4) void lsh_attn_k(
    const float* __restrict__ qk, const unsigned short* __restrict__ vbf,
    const int* __restrict__ st_sorted,
    unsigned short* __restrict__ so, float* __restrict__ slog)
{
    const int c = blockIdx.x;       // 0..127
    const int bh = blockIdx.y;      // 0..63
    const int b = bh >> 3, head = bh & 7;
    __shared__ unsigned short Ks[128 * 72];   // raw bf16 K rows, stride 72; Ps aliases after dots
    __shared__ unsigned short Vt[128 * 64];   // V^T [d][key], XOR-swizzled
    __shared__ float rnorm[128];
    __shared__ int stk[128];
    unsigned short* Ps = Ks;                  // P bf16 [q][key], stride 136 (64*136 <= 128*72)
    const int t = threadIdx.x;

    // ---- stage: K rows (bf16 raw) + rnorm + stk + Vt ----
    {
        const int r = t >> 1, hf = t & 1;
        const int cprev = (c + NCHUNK - 1) & (NCHUNK - 1);
        const int spos = (r < 64) ? (c * CS + r) : (cprev * CS + (r - 64));
        const int l = st_sorted[(size_t)bh * SORTN + spos];
        if (hf == 0) stk[r] = l;
        const size_t ro = (size_t)(b * 2048 + l) * 512 + head * 64 + hf * 32;
        const float4* q4 = reinterpret_cast<const float4*>(qk + ro);
        float ss = 0.f;
        #pragma unroll
        for (int u = 0; u < 8; ++u) {
            const float4 a = q4[u];
            ss += a.x*a.x + a.y*a.y + a.z*a.z + a.w*a.w;
            ushort4 pk;
            pk.x = f2bfu(a.x); pk.y = f2bfu(a.y); pk.z = f2bfu(a.z); pk.w = f2bfu(a.w);
            *reinterpret_cast<ushort4*>(&Ks[r * 72 + hf * 32 + u * 4]) = pk;
        }
        ss += __shfl_xor(ss, 1);
        if (hf == 0) rnorm[r] = 1.0f / fmaxf(sqrtf(ss), 1e-12f);
        // V^T: load 32 bf16 of row l, scatter to Vt[d][r] with XOR swizzle
        const uint4* v16 = reinterpret_cast<const uint4*>(vbf + ro);
        const uint4 a0 = v16[0], a1 = v16[1], a2 = v16[2], a3 = v16[3];
        const unsigned int wd[16] = {a0.x,a0.y,a0.z,a0.w, a1.x,a1.y,a1.z,a1.w,
                                     a2.x,a2.y,a2.z,a2.w, a3.x,a3.y,a3.z,a3.w};
        #pragma unroll
        for (int e = 0; e < 32; ++e) {
            const int d = hf * 32 + e;
            const unsigned short us = (unsigned short)(wd[e >> 1] >> ((e & 1) * 16));
            Vt[(d * 128 + r) ^ ((d & 7) << 3)] = us;
        }
    }
    __syncthreads();

    const int lane = t & 63, w = t >> 6;     // wave w owns q rows w*16..w*16+15
    const int fr = lane & 15, fq = lane >> 4;

    // ---- dots: S[16q x 128k] per wave, K-dim 64 (2 MFMA per k-tile) ----
    short8 aq[2];
    #pragma unroll
    for (int s = 0; s < 2; ++s)
        aq[s] = *reinterpret_cast<const short8*>(&Ks[(w * 16 + fr) * 72 + s * 32 + fq * 8]);
    f32x4 cc[8];
    #pragma unroll
    for (int n = 0; n < 8; ++n) cc[n] = (f32x4){0.f, 0.f, 0.f, 0.f};
    #pragma unroll
    for (int n = 0; n < 8; ++n) {
        #pragma unroll
        for (int s = 0; s < 2; ++s) {
            const short8 bk = *reinterpret_cast<const short8*>(
                &Ks[(n * 16 + fr) * 72 + s * 32 + fq * 8]);
            cc[n] = __builtin_amdgcn_mfma_f32_16x16x32_bf16(aq[s], bk, cc[n], 0, 0, 0);
        }
    }

    // ---- mask + scale + row softmax ----
    int stq_r[4];
    #pragma unroll
    for (int r = 0; r < 4; ++r) stq_r[r] = stk[w * 16 + fq * 4 + r];
    float mx[4] = {-3.0e38f, -3.0e38f, -3.0e38f, -3.0e38f};
    #pragma unroll
    for (int n = 0; n < 8; ++n) {
        const int key = n * 16 + fr;
        const float rn = rnorm[key] * 0.125f;
        const int sk = stk[key];
        #pragma unroll
        for (int r = 0; r < 4; ++r) {
            const float val = (stq_r[r] == sk) ? SELF_VAL : cc[n][r] * rn;
            cc[n][r] = val;
            mx[r] = fmaxf(mx[r], val);
        }
    }
    #pragma unroll
    for (int r = 0; r < 4; ++r) {
        mx[r] = fmaxf(mx[r], __shfl_xor(mx[r], 1));
        mx[r] = fmaxf(mx[r], __shfl_xor(mx[r], 2));
        mx[r] = fmaxf(mx[r], __shfl_xor(mx[r], 4));
        mx[r] = fmaxf(mx[r], __shfl_xor(mx[r], 8));
    }
    float sm[4] = {0.f, 0.f, 0.f, 0.f};
    #pragma unroll
    for (int n = 0; n < 8; ++n)
        #pragma unroll
        for (int r = 0; r < 4; ++r) {
            const float e = __expf(cc[n][r] - mx[r]);
            cc[n][r] = e;
            sm[r] += e;
        }
    #pragma unroll
    for (int r = 0; r < 4; ++r) {
        sm[r] += __shfl_xor(sm[r], 1);
        sm[r] += __shfl_xor(sm[r], 2);
        sm[r] += __shfl_xor(sm[r], 4);
        sm[r] += __shfl_xor(sm[r], 8);
    }
    float rsum[4];
    #pragma unroll
    for (int r = 0; r < 4; ++r) rsum[r] = 1.0f / sm[r];
    if (fr == 0) {
        #pragma unroll
        for (int r = 0; r < 4; ++r)
            slog[(size_t)bh * SORTN + c * CS + w * 16 + fq * 4 + r] = mx[r] + logf(sm[r]);
    }

    __syncthreads();   // all waves done reading Ks -> safe to overwrite with Ps

    // ---- P -> LDS bf16 [q][key] (into Ks space) ----
    #pragma unroll
    for (int n = 0; n < 8; ++n)
        #pragma unroll
        for (int r = 0; r < 4; ++r)
            Ps[(w * 16 + fq * 4 + r) * 136 + n * 16 + fr] = f2bfu(cc[n][r]);
    __syncthreads();

    // ---- PV: O[16q x 64d] = P[16q x 128k] @ V[128k x 64d] ----
    short8 pa[4];
    #pragma unroll
    for (int s = 0; s < 4; ++s)
        pa[s] = *reinterpret_cast<const short8*>(&Ps[(w * 16 + fr) * 136 + s * 32 + fq * 8]);
    f32x4 oo[4];
    #pragma unroll
    for (int n = 0; n < 4; ++n) oo[n] = (f32x4){0.f, 0.f, 0.f, 0.f};
    #pragma unroll
    for (int n = 0; n < 4; ++n) {
        const int d = n * 16 + fr;
        #pragma unroll
        for (int s = 0; s < 4; ++s) {
            const short8 vb = *reinterpret_cast<const short8*>(
                &Vt[(d * 128 + s * 32 + fq * 8) ^ ((d & 7) << 3)]);
            oo[n] = __builtin_amdgcn_mfma_f32_16x16x32_bf16(pa[s], vb, oo[n], 0, 0, 0);
        }
    }

    // ---- epilogue ----
    #pragma unroll
    for (int r = 0; r < 4; ++r) {
        const int qrow = w * 16 + fq * 4 + r;
        const size_t ob = ((size_t)bh * SORTN + c * CS + qrow) * 64;
        #pragma unroll
        for (int n = 0; n < 4; ++n)
            so[ob + n * 16 + fr] = f2bfu(oo[n][r] * rsum[r]);
    }
}

// ------------------------- unsort + hash-round combine (frozen) --------------
__global__ __launch_bounds__(256) void combine_k(
    const unsigned short* __restrict__ so, const float* __restrict__ slog,
    const int* __restrict__ pos_of, unsigned short* __restrict__ aout)
{
    const int gid = blockIdx.x * 256 + threadIdx.x;   // (bh,l) x 64d
    const int d = gid & 63;
    const int bl = gid >> 6;
    const int l = bl & 2047;
    const int bh = bl >> 11;
    const int b = bh >> 3, head = bh & 7;
    int pos[4]; float lg[4];
    #pragma unroll
    for (int hh = 0; hh < 4; ++hh) {
        pos[hh] = pos_of[((size_t)bh << 13) + hh * 2048 + l];
        lg[hh] = slog[((size_t)bh << 13) + pos[hh]];
    }
    const float m = fmaxf(fmaxf(lg[0], lg[1]), fmaxf(lg[2], lg[3]));
    float w[4]; float sw = 0.f;
    #pragma unroll
    for (int hh = 0; hh < 4; ++hh) { w[hh] = expf(lg[hh] - m); sw += w[hh]; }
    const float inv = 1.0f / sw;
    float acc = 0.f;
    #pragma unroll
    for (int hh = 0; hh < 4; ++hh)
        acc += w[hh] * bfu2f(so[(((size_t)bh << 13) + pos[hh]) * 64 + d]);
    aout[(size_t)(b * 2048 + l) * 512 + head * 64 + d] = f2bfu(acc * inv);
}

// ------------------------- residual + LayerNorm (frozen) ---------------------
template<int RES, int WBF>
__global__ __launch_bounds__(256) void ln_k(
    float* __restrict__ h, const float* __restrict__ res,
    const float* __restrict__ g, const float* __restrict__ bta,
    unsigned short* __restrict__ hb)
{
    const int row = blockIdx.x * 4 + (threadIdx.x >> 6);
    const int lane = threadIdx.x & 63;
    const size_t base = (size_t)row * 512;
    float4 xa = *reinterpret_cast<const float4*>(h + base + lane * 4);
    float4 xb = *reinterpret_cast<const float4*>(h + base + 256 + lane * 4);
    if (RES) {
        const float4 ra = *reinterpret_cast<const float4*>(res + base + lane * 4);
        const float4 rb = *reinterpret_cast<const float4*>(res + base + 256 + lane * 4);
        xa.x += ra.x; xa.y += ra.y; xa.z += ra.z; xa.w += ra.w;
        xb.x += rb.x; xb.y += rb.y; xb.z += rb.z; xb.w += rb.w;
    }
    float sum = xa.x + xa.y + xa.z + xa.w + xb.x + xb.y + xb.z + xb.w;
    float sq = xa.x*xa.x + xa.y*xa.y + xa.z*xa.z + xa.w*xa.w
             + xb.x*xb.x + xb.y*xb.y + xb.z*xb.z + xb.w*xb.w;
    #pragma unroll
    for (int off = 32; off > 0; off >>= 1) {
        sum += __shfl_xor(sum, off);
        sq  += __shfl_xor(sq, off);
    }
    const float mu = sum * (1.0f / 512.0f);
    const float var = sq * (1.0f / 512.0f) - mu * mu;
    const float rstd = rsqrtf(var + 1e-5f);
    const float4 ga = *reinterpret_cast<const float4*>(g + lane * 4);
    const float4 gb = *reinterpret_cast<const float4*>(g + 256 + lane * 4);
    const float4 ba = *reinterpret_cast<const float4*>(bta + lane * 4);
    const float4 bb = *reinterpret_cast<const float4*>(bta + 256 + lane * 4);
    float4 oa, ob;
    oa.x = (xa.x - mu) * rstd * ga.x + ba.x;
    oa.y = (xa.y - mu) * rstd * ga.y + ba.y;
    oa.z = (xa.z - mu) * rstd * ga.z + ba.z;
    oa.w = (xa.w - mu) * rstd * ga.w + ba.w;
    ob.x = (xb.x - mu) * rstd * gb.x + bb.x;
    ob.y = (xb.y - mu) * rstd * gb.y + bb.y;
    ob.z = (xb.z - mu) * rstd * gb.z + bb.z;
    ob.w = (xb.w - mu) * rstd * gb.w + bb.w;
    *reinterpret_cast<float4*>(h + base + lane * 4) = oa;
    *reinterpret_cast<float4*>(h + base + 256 + lane * 4) = ob;
    if (WBF) {
        ushort4 pa, pb;
        pa.x = f2bfu(oa.x); pa.y = f2bfu(oa.y); pa.z = f2bfu(oa.z); pa.w = f2bfu(oa.w);
        pb.x = f2bfu(ob.x); pb.y = f2bfu(ob.y); pb.z = f2bfu(ob.z); pb.w = f2bfu(ob.w);
        *reinterpret_cast<ushort4*>(hb + base + lane * 4) = pa;
        *reinterpret_cast<ushort4*>(hb + base + 256 + lane * 4) = pb;
    }
}

// ------------------------- final LN on consumed rows only --------------------
__global__ __launch_bounds__(256) void lnf_k(
    float* __restrict__ h, const float* __restrict__ g, const float* __restrict__ bta)
{
    const int vrow = blockIdx.x * 4 + (threadIdx.x >> 6);   // 0..4095
    const int row = (vrow >> 9) * 2048 + 1536 + (vrow & 511);
    const int lane = threadIdx.x & 63;
    const size_t base = (size_t)row * 512;
    float4 xa = *reinterpret_cast<const float4*>(h + base + lane * 4);
    float4 xb = *reinterpret_cast<const float4*>(h + base + 256 + lane * 4);
    float sum = xa.x + xa.y + xa.z + xa.w + xb.x + xb.y + xb.z + xb.w;
    float sq = xa.x*xa.x + xa.y*xa.y + xa.z*xa.z + xa.w*xa.w
             + xb.x*xb.x + xb.y*xb.y + xb.z*xb.z + xb.w*xb.w;
    #pragma unroll
    for (int off = 32; off > 0; off >>= 1) {
        sum += __shfl_xor(sum, off);
        sq  += __shfl_xor(sq, off);
    }
    const float mu = sum * (1.0f / 512.0f);
    const float var = sq * (1.0f / 512.0f) - mu * mu;
    const float rstd = rsqrtf(var + 1e-5f);
    const float4 ga = *reinterpret_cast<const float4*>(g + lane * 4);
    const float4 gb = *reinterpret_cast<const float4*>(g + 256 + lane * 4);
    const float4 ba = *reinterpret_cast<const float4*>(bta + lane * 4);
    const float4 bb = *reinterpret_cast<const float4*>(bta + 256 + lane * 4);
    float4 oa, ob;
    oa.x = (xa.x - mu) * rstd * ga.x + ba.x;
    oa.y = (xa.y - mu) * rstd * ga.y + ba.y;
    oa.z = (xa.z - mu) * rstd * ga.z + ba.z;
    oa.w = (xa.w - mu) * rstd * ga.w + ba.w;
    ob.x = (xb.x - mu) * rstd * gb.x + bb.x;
    ob.y = (xb.y - mu) * rstd * gb.y + bb.y;
    ob.z = (xb.z - mu) * rstd * gb.z + bb.z;
    ob.w = (xb.w - mu) * rstd * gb.w + bb.w;
    *reinterpret_cast<float4*>(h + base + lane * 4) = oa;
    *reinterpret_cast<float4*>(h + base + 256 + lane * 4) = ob;
}

// ------------------------- final projection (wave per token) -----------------
__global__ __launch_bounds__(256) void proj_k(
    const float* __restrict__ h, const float* __restrict__ pw,
    const float* __restrict__ pb, float* __restrict__ out)
{
    const int wid = (blockIdx.x * 256 + threadIdx.x) >> 6;  // 0..4095
    const int lane = threadIdx.x & 63;
    const int b = wid >> 9, tt = wid & 511;
    const float* row = h + (size_t)(b * 2048 + 1536 + tt) * 512;
    const float4 h0 = reinterpret_cast<const float4*>(row)[lane * 2];
    const float4 h1 = reinterpret_cast<const float4*>(row)[lane * 2 + 1];
    const float he[8] = {h0.x, h0.y, h0.z, h0.w, h1.x, h1.y, h1.z, h1.w};
    float acc[7] = {};
    #pragma unroll
    for (int e = 0; e < 8; ++e) {
        const int k = lane * 8 + e;
        #pragma unroll
        for (int cq = 0; cq < 7; ++cq) acc[cq] = fmaf(he[e], pw[k * 7 + cq], acc[cq]);
    }
    #pragma unroll
    for (int cq = 0; cq < 7; ++cq) {
        #pragma unroll
        for (int off = 32; off > 0; off >>= 1) acc[cq] += __shfl_xor(acc[cq], off);
    }
    if (lane == 0) {
        const size_t ob = ((size_t)(b * 512) + tt) * 7;
        #pragma unroll
        for (int cq = 0; cq < 7; ++cq) out[ob + cq] = acc[cq] + pb[cq];
    }
}

__global__ void nan_k(float* o) { o[0] = __int_as_float(0x7fc00000); }

// ---------------------------------------------------------------------------
extern "C" void kernel_launch(void* const* d_in, const int* in_sizes, int n_in,
                              void* d_out, int out_size, void* d_ws, size_t ws_size,
                              hipStream_t stream)
{
    const float* x_enc  = (const float*)d_in[0];
    const float* x_me   = (const float*)d_in[1];
    const float* x_dec  = (const float*)d_in[2];
    const float* x_md   = (const float*)d_in[3];
    const float* conv_w = (const float*)d_in[4];
    const float* time_w = (const float*)d_in[5];
    const float* qk_w   = (const float*)d_in[6];
    const float* v_w    = (const float*)d_in[7];
    const float* out_w  = (const float*)d_in[8];
    const float* out_b  = (const float*)d_in[9];
    const float* rots   = (const float*)d_in[10];
    const float* f1w    = (const float*)d_in[11];
    const float* f1b    = (const float*)d_in[12];
    const float* f2w    = (const float*)d_in[13];
    const float* f2b    = (const float*)d_in[14];
    const float* n1g    = (const float*)d_in[15];
    const float* n1b    = (const float*)d_in[16];
    const float* n2g    = (const float*)d_in[17];
    const float* n2b    = (const float*)d_in[18];
    const float* nfg    = (const float*)d_in[19];
    const float* nfb    = (const float*)d_in[20];
    const float* pw     = (const float*)d_in[21];
    const float* pb     = (const float*)d_in[22];

    // workspace layout (bytes) — identical to R3/R5/R6/R8
    char* ws = (char*)d_ws;
    const size_t HBYT = (size_t)ROWS * DM * 4;                   // 33.5 MB
    float* h    = (float*)ws;                  ws += HBYT;
    unsigned short* hb = (unsigned short*)ws;  ws += HBYT / 2;   // bf16 h
    float* qkb  = (float*)ws;                  ws += HBYT;       // qk fp32; ab (bf16) aliases
    float* gout = (float*)ws;                  ws += HBYT;       // GEMM fp32 out; vbf aliases
    unsigned short* mid = (unsigned short*)ws; ws += (size_t)ROWS * DFF * 2; // 67MB, also 'so'
    float* slog = (float*)ws;                  ws += (size_t)BHN * SORTN * 4;
    int* buckets = (int*)ws;                   ws += (size_t)BHN * SORTN * 4;
    int* st_sorted = (int*)ws;                 ws += (size_t)BHN * SORTN * 4;
    int* pos_of = (int*)ws;                    ws += (size_t)BHN * SORTN * 4;
    unsigned short* wT = (unsigned short*)ws;  ws += (size_t)(2*262144 + 2*262144 + 2*1048576 + 2*1048576) * 2;
    const size_t need = (size_t)(ws - (char*)d_ws);
    if (ws_size < need) { nan_k<<<1, 1, 0, stream>>>((float*)d_out); return; }

    unsigned short* vT  = wT;                 // [l][512][512]
    unsigned short* oT  = vT + 2 * 262144;    // [l][512][512]
    unsigned short* f1T = oT + 2 * 262144;    // [l][2048][512]
    unsigned short* f2T = f1T + 2 * 1048576;  // [l][512][2048]
    unsigned short* ab  = (unsigned short*)qkb;   // bf16 attn output (aliases qk)
    unsigned short* vbf = (unsigned short*)gout;  // bf16 v (aliases gout)

    // weight transpose-casts (bf16, [N][K]); z = layer
    tcast_k<<<dim3(16, 16, 2), 256, 0, stream>>>(v_w,   vT,  DM, DM);
    tcast_k<<<dim3(16, 16, 2), 256, 0, stream>>>(out_w, oT,  DM, DM);
    tcast_k<<<dim3(16, 64, 2), 256, 0, stream>>>(f1w,   f1T, DM, DFF);
    tcast_k<<<dim3(64, 16, 2), 256, 0, stream>>>(f2w,   f2T, DFF, DM);

    embed_k<<<ROWS, 512, 0, stream>>>(x_enc, x_me, x_dec, x_md, conv_w, time_w, h, hb);

    for (int l = 0; l < 2; ++l) {
        const size_t wo = (size_t)l * DM * DM;
        // qk: fp32 (hash argmax is a discrete decision); v: bf16 MFMA
        gemm_k<<<dim3(ROWS/128, DM/64), 256, 0, stream>>>(h, qk_w + wo, qkb, ROWS, DM, DM);
        mgemm_k<1,0,0><<<dim3(ROWS/128, DM/128), 256, 0, stream>>>(hb, vT + (size_t)l*262144, nullptr, vbf, DM, DM);
        // LSH hash + stable sort
        hash_k<<<(NHASH * BHN * SEQL) / 256, 256, 0, stream>>>(qkb, rots + (size_t)l * DH * NHASH * (NBUCK/2), buckets);
        sort_k<<<BHN * 4, 256, 0, stream>>>(buckets, st_sorted, pos_of);
        // MFMA chunked attention (sorted order), unsort + combine
        lsh_attn_k<<<dim3(NCHUNK, BHN), 256, 0, stream>>>(qkb, vbf, st_sorted, mid /*so*/, slog);
        combine_k<<<(BHN * SEQL * DH) / 256, 256, 0, stream>>>(mid, slog, pos_of, ab);
        // output projection + residual LN
        mgemm_k<0,0,1><<<dim3(ROWS/128, DM/128), 256, 0, stream>>>(ab, oT + (size_t)l*262144, out_b + l * DM, gout, DM, DM);
        ln_k<1,1><<<ROWS/4, 256, 0, stream>>>(h, gout, n1g + l * DM, n1b + l * DM, hb);
        // FFN (bf16 MFMA)
        mgemm_k<1,1,1><<<dim3(ROWS/128, DFF/128), 256, 0, stream>>>(hb, f1T + (size_t)l*1048576, f1b + l * DFF, mid, DFF, DM);
        mgemm_k<0,0,1><<<dim3(ROWS/128, DM/128), 256, 0, stream>>>(mid, f2T + (size_t)l*1048576, f2b + l * DM, gout, DM, DFF);
        ln_k<1,1><<<ROWS/4, 256, 0, stream>>>(h, gout, n2g + l * DM, n2b + l * DM, hb);
    }
    lnf_k<<<(BATCH * 512) / 4, 256, 0, stream>>>(h, nfg, nfb);
    proj_k<<<(BATCH * 512 / 4), 256, 0, stream>>>(h, pw, pb, (float*)d_out);
}

// Round 10
// 956.881 us; speedup vs baseline: 1.0190x; 1.0190x over previous
//
#include <hip/hip_runtime.h>

// ---------------------------------------------------------------------------
// Model_16690242912472: Reformer-style forecaster.
// B=8, L=2048, D_MODEL=512, H=8, DH=64, DFF=2048, 2 layers,
// LSH attn: 4 hashes, 32 buckets, bucket_size 64 -> 128 chunks of 64.
// R10: gemm_k 64x64 tile (2048 blocks, 8/CU, LDS 8.5KB, acc 4x4) — same
// ascending-k fmaf chain per output => bit-identical hash inputs. BK=32
// reverted (R9: occupancy regression). lsh_attn keeps R9 Ps-alias.
// ---------------------------------------------------------------------------

#define BATCH 8
#define SEQL 2048
#define DM 512
#define NH 8
#define DH 64
#define DFF 2048
#define NHASH 4
#define NBUCK 32
#define NCHUNK 128   // NHASH*NBUCK
#define CS 64        // chunk size
#define ROWS (BATCH*SEQL)      // 16384
#define BHN (BATCH*NH)         // 64
#define SORTN (NHASH*SEQL)     // 8192
#define SELF_VAL -5e4f

typedef __attribute__((ext_vector_type(4))) float f32x4;
typedef __attribute__((ext_vector_type(8))) short short8;

__device__ __forceinline__ float bfu2f(unsigned int u16) {
    return __uint_as_float(u16 << 16);
}
__device__ __forceinline__ unsigned short f2bfu(float f) {
    unsigned int x = __float_as_uint(f);
    x += 0x7fffu + ((x >> 16) & 1u);   // RNE (inputs finite)
    return (unsigned short)(x >> 16);
}

__device__ __forceinline__ void gld16(const void* g, void* l) {
    __builtin_amdgcn_global_load_lds(
        (const __attribute__((address_space(1))) unsigned int*)g,
        (__attribute__((address_space(3))) unsigned int*)l, 16, 0, 0);
}

// ------------------------- embedding (frozen) --------------------------------
__device__ __forceinline__ float getx(const float* xe, const float* xd, int b, int lm, int c) {
    return (lm < 1536) ? xe[((size_t)b * 1536 + lm) * 7 + c]
                       : xd[((size_t)b * 1024 + (lm - 1024)) * 7 + c];
}

__global__ __launch_bounds__(512) void embed_k(
    const float* __restrict__ x_enc, const float* __restrict__ x_me,
    const float* __restrict__ x_dec, const float* __restrict__ x_md,
    const float* __restrict__ cw, const float* __restrict__ tw,
    float* __restrict__ h, unsigned short* __restrict__ hb)
{
    const int row = blockIdx.x;            // 0..16383
    const int b = row >> 11, l = row & 2047;
    const int d = threadIdx.x;             // 0..511
    __shared__ float xs[21];
    __shared__ float xms[4];
    if (d < 21) {
        const int k = d / 7, c = d % 7;
        const int lm = (l + k + 2047) & 2047;   // l-1+k circular
        xs[d] = getx(x_enc, x_dec, b, lm, c);
    } else if (d < 25) {
        const int m = d - 21;
        xms[m] = (l < 1536) ? x_me[((size_t)b * 1536 + l) * 4 + m]
                            : x_md[((size_t)b * 1024 + (l - 1024)) * 4 + m];
    }
    __syncthreads();
    float tok = 0.f;
    #pragma unroll
    for (int kc = 0; kc < 21; ++kc) tok = fmaf(xs[kc], cw[kc * 512 + d], tok);
    float tm = 0.f;
    #pragma unroll
    for (int m = 0; m < 4; ++m) tm = fmaf(xms[m], tw[m * 512 + d], tm);
    const int pair = d & ~1;
    const float freq = expf((float)pair * (-9.210340371976184f / 512.f)); // ln(1e4)
    const float ang = (float)l * freq;
    const float pe = (d & 1) ? cosf(ang) : sinf(ang);
    const float val = tok + pe + tm;
    h[(size_t)row * 512 + d] = val;
    hb[(size_t)row * 512 + d] = f2bfu(val);
}

// ------------------------- fp32 GEMM (qk/hash path) -------------------------
// 64x64 tile, BK=16, reg prefetch, 2048 blocks (8/CU). Per-output
// accumulation: one fmaf per k, ascending k -> bit-identical chain.
__global__ __launch_bounds__(256) void gemm_k(
    const float* __restrict__ A, const float* __restrict__ B,
    float* __restrict__ C, int M, int N, int K)
{
    __shared__ float As[16][68];
    __shared__ float Bs[16][64];
    const int tid = threadIdx.x;
    const int bm = blockIdx.x * 64, bn = blockIdx.y * 64;
    const int ty = tid >> 4, tx = tid & 15;         // 16x16 threads, 4x4 acc
    const int ar = tid >> 2, ac = (tid & 3) * 4;    // A: 64 rows x 16 k
    const int br = tid >> 4, bc = (tid & 15) * 4;   // B: 16 rows x 64 n
    float acc[4][4] = {};
    const float* Ap = A + (size_t)(bm + ar) * K + ac;
    const float* Bp = B + (size_t)br * N + bn + bc;
    float4 a0v = *reinterpret_cast<const float4*>(Ap);
    float4 b0v = *reinterpret_cast<const float4*>(Bp);
    for (int k0 = 0; k0 < K; k0 += 16) {
        As[ac + 0][ar] = a0v.x; As[ac + 1][ar] = a0v.y;
        As[ac + 2][ar] = a0v.z; As[ac + 3][ar] = a0v.w;
        *reinterpret_cast<float4*>(&Bs[br][bc]) = b0v;
        __syncthreads();
        if (k0 + 16 < K) {
            a0v = *reinterpret_cast<const float4*>(Ap + k0 + 16);
            b0v = *reinterpret_cast<const float4*>(Bp + (size_t)(k0 + 16) * N);
        }
        #pragma unroll
        for (int k = 0; k < 16; ++k) {
            const float4 a0 = *reinterpret_cast<const float4*>(&As[k][ty * 4]);
            const float4 b0 = *reinterpret_cast<const float4*>(&Bs[k][tx * 4]);
            const float a[4] = {a0.x, a0.y, a0.z, a0.w};
            const float bb[4] = {b0.x, b0.y, b0.z, b0.w};
            #pragma unroll
            for (int i = 0; i < 4; ++i)
                #pragma unroll
                for (int j = 0; j < 4; ++j) acc[i][j] = fmaf(a[i], bb[j], acc[i][j]);
        }
        __syncthreads();
    }
    #pragma unroll
    for (int i = 0; i < 4; ++i) {
        const size_t cb = (size_t)(bm + ty * 4 + i) * N + bn + tx * 4;
        *reinterpret_cast<float4*>(C + cb) = make_float4(acc[i][0],acc[i][1],acc[i][2],acc[i][3]);
    }
}

// ------------------------- weight transpose-cast (z = layer) -----------------
__global__ __launch_bounds__(256) void tcast_k(
    const float* __restrict__ W, unsigned short* __restrict__ Wt, int K, int N)
{
    __shared__ float t[32][33];
    const size_t zo = (size_t)blockIdx.z * K * N;
    const int kb = blockIdx.x * 32, nb = blockIdx.y * 32;
    const int tx = threadIdx.x & 31, ty = threadIdx.x >> 5;
    #pragma unroll
    for (int i = ty; i < 32; i += 8)
        t[i][tx] = W[zo + (size_t)(kb + i) * N + nb + tx];
    __syncthreads();
    #pragma unroll
    for (int i = ty; i < 32; i += 8)
        Wt[zo + (size_t)(nb + i) * K + kb + tx] = f2bfu(t[tx][i]);
}

// ------------------------- bf16 MFMA GEMM (R6-verbatim) ----------------------
template<int OUT_BF, int ACT, int BIAS>
__global__ __launch_bounds__(256) void mgemm_k(
    const unsigned short* __restrict__ A,
    const unsigned short* __restrict__ Bt,
    const float* __restrict__ bias,
    void* __restrict__ Cv, int N, int K)
{
    __shared__ unsigned short As[128 * 32];
    __shared__ unsigned short Bs[128 * 32];
    const int tid = threadIdx.x;
    const int bm = blockIdx.x * 128, bn = blockIdx.y * 128;
    const int lane = tid & 63, w = tid >> 6;
    const int wr = (w >> 1) * 64, wc = (w & 1) * 64;
    const int fr = lane & 15, fq = lane >> 4;
    const int r0 = tid >> 2, c0 = (tid & 3) * 8;
    const unsigned short* Ag = A + (size_t)(bm + r0) * K + c0;
    const unsigned short* Bg = Bt + (size_t)(bn + r0) * K + c0;
    f32x4 acc[4][4];
    #pragma unroll
    for (int i = 0; i < 4; ++i)
        #pragma unroll
        for (int j = 0; j < 4; ++j) acc[i][j] = (f32x4){0.f, 0.f, 0.f, 0.f};
    for (int k0 = 0; k0 < K; k0 += 32) {
        gld16(Ag + k0,                   As + tid * 8);
        gld16(Ag + (size_t)64 * K + k0,  As + tid * 8 + 2048);
        gld16(Bg + k0,                   Bs + tid * 8);
        gld16(Bg + (size_t)64 * K + k0,  Bs + tid * 8 + 2048);
        __syncthreads();
        short8 af[4], bfr[4];
        #pragma unroll
        for (int mi = 0; mi < 4; ++mi)
            af[mi] = *reinterpret_cast<const short8*>(As + (wr + mi * 16 + fr) * 32 + fq * 8);
        #pragma unroll
        for (int ni = 0; ni < 4; ++ni)
            bfr[ni] = *reinterpret_cast<const short8*>(Bs + (wc + ni * 16 + fr) * 32 + fq * 8);
        #pragma unroll
        for (int mi = 0; mi < 4; ++mi)
            #pragma unroll
            for (int ni = 0; ni < 4; ++ni)
                acc[mi][ni] = __builtin_amdgcn_mfma_f32_16x16x32_bf16(
                    af[mi], bfr[ni], acc[mi][ni], 0, 0, 0);
        __syncthreads();
    }
    float bv[4];
    if (BIAS) {
        #pragma unroll
        for (int ni = 0; ni < 4; ++ni) bv[ni] = bias[bn + wc + ni * 16 + fr];
    }
    #pragma unroll
    for (int mi = 0; mi < 4; ++mi) {
        #pragma unroll
        for (int r = 0; r < 4; ++r) {
            const int row = bm + wr + mi * 16 + fq * 4 + r;
            #pragma unroll
            for (int ni = 0; ni < 4; ++ni) {
                float val = acc[mi][ni][r];
                if (BIAS) val += bv[ni];
                if (ACT) val = 0.5f * val * (1.0f + erff(val * 0.7071067811865475f));
                const size_t idx = (size_t)row * N + bn + wc + ni * 16 + fr;
                if (OUT_BF) ((unsigned short*)Cv)[idx] = f2bfu(val);
                else        ((float*)Cv)[idx] = val;
            }
        }
    }
}

// ------------------------- LSH hashing (frozen, R8-verbatim) -----------------
__global__ __launch_bounds__(256, 4) void hash_k(
    const float* __restrict__ qk, const float* __restrict__ rot,
    int* __restrict__ buckets)
{
    __shared__ float rs[16][68];   // [j][d], padded
    const int t = threadIdx.x;
    const int hh_blk = blockIdx.x >> 9;      // 512 blocks per hh
    for (int u = t; u < 1024; u += 256) {
        const int d = u >> 4, j = u & 15;    // rot layout: d*64 + hh*16 + j
        rs[j][d] = rot[d * 64 + hh_blk * 16 + j];
    }
    __syncthreads();
    const int gid = blockIdx.x * 256 + t;    // 0..524287 = (hh, bh, l)
    const int l = gid & 2047;
    const int bh = (gid >> 11) & 63;
    const int hh = gid >> 17;                // == hh_blk
    const int b = bh >> 3, head = bh & 7;
    const float* qrow = qk + (size_t)(b * 2048 + l) * 512 + head * 64;
    float q[64];
    #pragma unroll
    for (int d4 = 0; d4 < 16; ++d4) {
        const float4 qq = reinterpret_cast<const float4*>(qrow)[d4];
        q[d4*4+0]=qq.x; q[d4*4+1]=qq.y; q[d4*4+2]=qq.z; q[d4*4+3]=qq.w;
    }
    float bvp = -1e38f, bvn = -1e38f;
    int bip = 0, bin_ = 16;
    #pragma unroll
    for (int j = 0; j < 16; ++j) {
        float dot = 0.f;
        #pragma unroll
        for (int d = 0; d < 64; d += 4) {
            const float4 r = *reinterpret_cast<const float4*>(&rs[j][d]);
            dot += q[d]*r.x + q[d+1]*r.y + q[d+2]*r.z + q[d+3]*r.w;
        }
        if (dot  > bvp) { bvp = dot;  bip = j; }
        if (-dot > bvn) { bvn = -dot; bin_ = 16 + j; }
    }
    const int idx = (bvn > bvp) ? bin_ : bip;   // ties -> + block (lower idx)
    buckets[((size_t)bh << 13) + hh * 2048 + l] = hh * 32 + idx;
}

// ------------------------- stable counting sort (frozen) ---------------------
__global__ __launch_bounds__(256) void sort_k(
    const int* __restrict__ buckets, int* __restrict__ st_sorted, int* __restrict__ pos_of)
{
    const int bh = blockIdx.x >> 2, hh = blockIdx.x & 3;
    const int t = threadIdx.x;
    __shared__ unsigned short cnt[256][32];
    __shared__ int tot[32];
    __shared__ int startc[32];
    {
        uint4* p = reinterpret_cast<uint4*>(&cnt[t][0]);
        const uint4 z = {0,0,0,0};
        #pragma unroll
        for (int q = 0; q < 4; ++q) p[q] = z;
    }
    const size_t base = (size_t)bh * SORTN + hh * 2048;
    int myb[8];
    #pragma unroll
    for (int j = 0; j < 8; ++j) {
        const int i = t * 8 + j;
        const int g = buckets[base + i] - hh * 32;
        myb[j] = g;
        cnt[t][g]++;
    }
    __syncthreads();
    if (t < 32) {
        int run = 0;
        for (int tt = 0; tt < 256; ++tt) {
            const int x = cnt[tt][t];
            cnt[tt][t] = (unsigned short)run;
            run += x;
        }
        tot[t] = run;
    }
    __syncthreads();
    if (t == 0) {
        int s = 0;
        for (int g = 0; g < 32; ++g) { startc[g] = s; s += tot[g]; }
    }
    __syncthreads();
    #pragma unroll
    for (int j = 0; j < 8; ++j) {
        const int i = t * 8 + j;
        const int g = myb[j];
        const int rank = cnt[t][g]++;
        const int pos = hh * 2048 + startc[g] + rank;
        st_sorted[(size_t)bh * SORTN + pos] = i;   // i == l within this hash round
        pos_of[base + i] = pos;
    }
}

// ------------------------- MFMA chunked LSH attention (R9-verbatim) ----------
__global__ __launch_bounds__(256, 4) void lsh_attn_k(
    const float* __restrict__ qk, const unsigned short* __restrict__ vbf,
    const int* __restrict__ st_sorted,
    unsigned short* __restrict__ so, float* __restrict__ slog)
{
    const int c = blockIdx.x;       // 0..127
    const int bh = blockIdx.y;      // 0..63
    const int b = bh >> 3, head = bh & 7;
    __shared__ unsigned short Ks[128 * 72];   // raw bf16 K rows, stride 72; Ps aliases after dots
    __shared__ unsigned short Vt[128 * 64];   // V^T [d][key], XOR-swizzled
    __shared__ float rnorm[128];
    __shared__ int stk[128];
    unsigned short* Ps = Ks;                  // P bf16 [q][key], stride 136 (64*136 <= 128*72)
    const int t = threadIdx.x;

    // ---- stage: K rows (bf16 raw) + rnorm + stk + Vt ----
    {
        const int r = t >> 1, hf = t & 1;
        const int cprev = (c + NCHUNK - 1) & (NCHUNK - 1);
        const int spos = (r < 64) ? (c * CS + r) : (cprev * CS + (r - 64));
        const int l = st_sorted[(size_t)bh * SORTN + spos];
        if (hf == 0) stk[r] = l;
        const size_t ro = (size_t)(b * 2048 + l) * 512 + head * 64 + hf * 32;
        const float4* q4 = reinterpret_cast<const float4*>(qk + ro);
        float ss = 0.f;
        #pragma unroll
        for (int u = 0; u < 8; ++u) {
            const float4 a = q4[u];
            ss += a.x*a.x + a.y*a.y + a.z*a.z + a.w*a.w;
            ushort4 pk;
            pk.x = f2bfu(a.x); pk.y = f2bfu(a.y); pk.z = f2bfu(a.z); pk.w = f2bfu(a.w);
            *reinterpret_cast<ushort4*>(&Ks[r * 72 + hf * 32 + u * 4]) = pk;
        }
        ss += __shfl_xor(ss, 1);
        if (hf == 0) rnorm[r] = 1.0f / fmaxf(sqrtf(ss), 1e-12f);
        // V^T: load 32 bf16 of row l, scatter to Vt[d][r] with XOR swizzle
        const uint4* v16 = reinterpret_cast<const uint4*>(vbf + ro);
        const uint4 a0 = v16[0], a1 = v16[1], a2 = v16[2], a3 = v16[3];
        const unsigned int wd[16] = {a0.x,a0.y,a0.z,a0.w, a1.x,a1.y,a1.z,a1.w,
                                     a2.x,a2.y,a2.z,a2.w, a3.x,a3.y,a3.z,a3.w};
        #pragma unroll
        for (int e = 0; e < 32; ++e) {
            const int d = hf * 32 + e;
            const unsigned short us = (unsigned short)(wd[e >> 1] >> ((e & 1) * 16));
            Vt[(d * 128 + r) ^ ((d & 7) << 3)] = us;
        }
    }
    __syncthreads();

    const int lane = t & 63, w = t >> 6;     // wave w owns q rows w*16..w*16+15
    const int fr = lane & 15, fq = lane >> 4;

    // ---- dots: S[16q x 128k] per wave, K-dim 64 (2 MFMA per k-tile) ----
    short8 aq[2];
    #pragma unroll
    for (int s = 0; s < 2; ++s)
        aq[s] = *reinterpret_cast<const short8*>(&Ks[(w * 16 + fr) * 72 + s * 32 + fq * 8]);
    f32x4 cc[8];
    #pragma unroll
    for (int n = 0; n < 8; ++n) cc[n] = (f32x4){0.f, 0.f, 0.f, 0.f};
    #pragma unroll
    for (int n = 0; n < 8; ++n) {
        #pragma unroll
        for (int s = 0; s < 2; ++s) {
            const short8 bk = *reinterpret_cast<const short8*>(
                &Ks[(n * 16 + fr) * 72 + s * 32 + fq * 8]);
            cc[n] = __builtin_amdgcn_mfma_f32_16x16x32_bf16(aq[s], bk, cc[n], 0, 0, 0);
        }
    }

    // ---- mask + scale + row softmax ----
    int stq_r[4];
    #pragma unroll
    for (int r = 0; r < 4; ++r) stq_r[r] = stk[w * 16 + fq * 4 + r];
    float mx[4] = {-3.0e38f, -3.0e38f, -3.0e38f, -3.0e38f};
    #pragma unroll
    for (int n = 0; n < 8; ++n) {
        const int key = n * 16 + fr;
        const float rn = rnorm[key] * 0.125f;
        const int sk = stk[key];
        #pragma unroll
        for (int r = 0; r < 4; ++r) {
            const float val = (stq_r[r] == sk) ? SELF_VAL : cc[n][r] * rn;
            cc[n][r] = val;
            mx[r] = fmaxf(mx[r], val);
        }
    }
    #pragma unroll
    for (int r = 0; r < 4; ++r) {
        mx[r] = fmaxf(mx[r], __shfl_xor(mx[r], 1));
        mx[r] = fmaxf(mx[r], __shfl_xor(mx[r], 2));
        mx[r] = fmaxf(mx[r], __shfl_xor(mx[r], 4));
        mx[r] = fmaxf(mx[r], __shfl_xor(mx[r], 8));
    }
    float sm[4] = {0.f, 0.f, 0.f, 0.f};
    #pragma unroll
    for (int n = 0; n < 8; ++n)
        #pragma unroll
        for (int r = 0; r < 4; ++r) {
            const float e = __expf(cc[n][r] - mx[r]);
            cc[n][r] = e;
            sm[r] += e;
        }
    #pragma unroll
    for (int r = 0; r < 4; ++r) {
        sm[r] += __shfl_xor(sm[r], 1);
        sm[r] += __shfl_xor(sm[r], 2);
        sm[r] += __shfl_xor(sm[r], 4);
        sm[r] += __shfl_xor(sm[r], 8);
    }
    float rsum[4];
    #pragma unroll
    for (int r = 0; r < 4; ++r) rsum[r] = 1.0f / sm[r];
    if (fr == 0) {
        #pragma unroll
        for (int r = 0; r < 4; ++r)
            slog[(size_t)bh * SORTN + c * CS + w * 16 + fq * 4 + r] = mx[r] + logf(sm[r]);
    }

    __syncthreads();   // all waves done reading Ks -> safe to overwrite with Ps

    // ---- P -> LDS bf16 [q][key] (into Ks space) ----
    #pragma unroll
    for (int n = 0; n < 8; ++n)
        #pragma unroll
        for (int r = 0; r < 4; ++r)
            Ps[(w * 16 + fq * 4 + r) * 136 + n * 16 + fr] = f2bfu(cc[n][r]);
    __syncthreads();

    // ---- PV: O[16q x 64d] = P[16q x 128k] @ V[128k x 64d] ----
    short8 pa[4];
    #pragma unroll
    for (int s = 0; s < 4; ++s)
        pa[s] = *reinterpret_cast<const short8*>(&Ps[(w * 16 + fr) * 136 + s * 32 + fq * 8]);
    f32x4 oo[4];
    #pragma unroll
    for (int n = 0; n < 4; ++n) oo[n] = (f32x4){0.f, 0.f, 0.f, 0.f};
    #pragma unroll
    for (int n = 0; n < 4; ++n) {
        const int d = n * 16 + fr;
        #pragma unroll
        for (int s = 0; s < 4; ++s) {
            const short8 vb = *reinterpret_cast<const short8*>(
                &Vt[(d * 128 + s * 32 + fq * 8) ^ ((d & 7) << 3)]);
            oo[n] = __builtin_amdgcn_mfma_f32_16x16x32_bf16(pa[s], vb, oo[n], 0, 0, 0);
        }
    }

    // ---- epilogue ----
    #pragma unroll
    for (int r = 0; r < 4; ++r) {
        const int qrow = w * 16 + fq * 4 + r;
        const size_t ob = ((size_t)bh * SORTN + c * CS + qrow) * 64;
        #pragma unroll
        for (int n = 0; n < 4; ++n)
            so[ob + n * 16 + fr] = f2bfu(oo[n][r] * rsum[r]);
    }
}

// ------------------------- unsort + hash-round combine (frozen) --------------
__global__ __launch_bounds__(256) void combine_k(
    const unsigned short* __restrict__ so, const float* __restrict__ slog,
    const int* __restrict__ pos_of, unsigned short* __restrict__ aout)
{
    const int gid = blockIdx.x * 256 + threadIdx.x;   // (bh,l) x 64d
    const int d = gid & 63;
    const int bl = gid >> 6;
    const int l = bl & 2047;
    const int bh = bl >> 11;
    const int b = bh >> 3, head = bh & 7;
    int pos[4]; float lg[4];
    #pragma unroll
    for (int hh = 0; hh < 4; ++hh) {
        pos[hh] = pos_of[((size_t)bh << 13) + hh * 2048 + l];
        lg[hh] = slog[((size_t)bh << 13) + pos[hh]];
    }
    const float m = fmaxf(fmaxf(lg[0], lg[1]), fmaxf(lg[2], lg[3]));
    float w[4]; float sw = 0.f;
    #pragma unroll
    for (int hh = 0; hh < 4; ++hh) { w[hh] = expf(lg[hh] - m); sw += w[hh]; }
    const float inv = 1.0f / sw;
    float acc = 0.f;
    #pragma unroll
    for (int hh = 0; hh < 4; ++hh)
        acc += w[hh] * bfu2f(so[(((size_t)bh << 13) + pos[hh]) * 64 + d]);
    aout[(size_t)(b * 2048 + l) * 512 + head * 64 + d] = f2bfu(acc * inv);
}

// ------------------------- residual + LayerNorm (frozen) ---------------------
template<int RES, int WBF>
__global__ __launch_bounds__(256) void ln_k(
    float* __restrict__ h, const float* __restrict__ res,
    const float* __restrict__ g, const float* __restrict__ bta,
    unsigned short* __restrict__ hb)
{
    const int row = blockIdx.x * 4 + (threadIdx.x >> 6);
    const int lane = threadIdx.x & 63;
    const size_t base = (size_t)row * 512;
    float4 xa = *reinterpret_cast<const float4*>(h + base + lane * 4);
    float4 xb = *reinterpret_cast<const float4*>(h + base + 256 + lane * 4);
    if (RES) {
        const float4 ra = *reinterpret_cast<const float4*>(res + base + lane * 4);
        const float4 rb = *reinterpret_cast<const float4*>(res + base + 256 + lane * 4);
        xa.x += ra.x; xa.y += ra.y; xa.z += ra.z; xa.w += ra.w;
        xb.x += rb.x; xb.y += rb.y; xb.z += rb.z; xb.w += rb.w;
    }
    float sum = xa.x + xa.y + xa.z + xa.w + xb.x + xb.y + xb.z + xb.w;
    float sq = xa.x*xa.x + xa.y*xa.y + xa.z*xa.z + xa.w*xa.w
             + xb.x*xb.x + xb.y*xb.y + xb.z*xb.z + xb.w*xb.w;
    #pragma unroll
    for (int off = 32; off > 0; off >>= 1) {
        sum += __shfl_xor(sum, off);
        sq  += __shfl_xor(sq, off);
    }
    const float mu = sum * (1.0f / 512.0f);
    const float var = sq * (1.0f / 512.0f) - mu * mu;
    const float rstd = rsqrtf(var + 1e-5f);
    const float4 ga = *reinterpret_cast<const float4*>(g + lane * 4);
    const float4 gb = *reinterpret_cast<const float4*>(g + 256 + lane * 4);
    const float4 ba = *reinterpret_cast<const float4*>(bta + lane * 4);
    const float4 bb = *reinterpret_cast<const float4*>(bta + 256 + lane * 4);
    float4 oa, ob;
    oa.x = (xa.x - mu) * rstd * ga.x + ba.x;
    oa.y = (xa.y - mu) * rstd * ga.y + ba.y;
    oa.z = (xa.z - mu) * rstd * ga.z + ba.z;
    oa.w = (xa.w - mu) * rstd * ga.w + ba.w;
    ob.x = (xb.x - mu) * rstd * gb.x + bb.x;
    ob.y = (xb.y - mu) * rstd * gb.y + bb.y;
    ob.z = (xb.z - mu) * rstd * gb.z + bb.z;
    ob.w = (xb.w - mu) * rstd * gb.w + bb.w;
    *reinterpret_cast<float4*>(h + base + lane * 4) = oa;
    *reinterpret_cast<float4*>(h + base + 256 + lane * 4) = ob;
    if (WBF) {
        ushort4 pa, pb;
        pa.x = f2bfu(oa.x); pa.y = f2bfu(oa.y); pa.z = f2bfu(oa.z); pa.w = f2bfu(oa.w);
        pb.x = f2bfu(ob.x); pb.y = f2bfu(ob.y); pb.z = f2bfu(ob.z); pb.w = f2bfu(ob.w);
        *reinterpret_cast<ushort4*>(hb + base + lane * 4) = pa;
        *reinterpret_cast<ushort4*>(hb + base + 256 + lane * 4) = pb;
    }
}

// ------------------------- final LN on consumed rows only --------------------
__global__ __launch_bounds__(256) void lnf_k(
    float* __restrict__ h, const float* __restrict__ g, const float* __restrict__ bta)
{
    const int vrow = blockIdx.x * 4 + (threadIdx.x >> 6);   // 0..4095
    const int row = (vrow >> 9) * 2048 + 1536 + (vrow & 511);
    const int lane = threadIdx.x & 63;
    const size_t base = (size_t)row * 512;
    float4 xa = *reinterpret_cast<const float4*>(h + base + lane * 4);
    float4 xb = *reinterpret_cast<const float4*>(h + base + 256 + lane * 4);
    float sum = xa.x + xa.y + xa.z + xa.w + xb.x + xb.y + xb.z + xb.w;
    float sq = xa.x*xa.x + xa.y*xa.y + xa.z*xa.z + xa.w*xa.w
             + xb.x*xb.x + xb.y*xb.y + xb.z*xb.z + xb.w*xb.w;
    #pragma unroll
    for (int off = 32; off > 0; off >>= 1) {
        sum += __shfl_xor(sum, off);
        sq  += __shfl_xor(sq, off);
    }
    const float mu = sum * (1.0f / 512.0f);
    const float var = sq * (1.0f / 512.0f) - mu * mu;
    const float rstd = rsqrtf(var + 1e-5f);
    const float4 ga = *reinterpret_cast<const float4*>(g + lane * 4);
    const float4 gb = *reinterpret_cast<const float4*>(g + 256 + lane * 4);
    const float4 ba = *reinterpret_cast<const float4*>(bta + lane * 4);
    const float4 bb = *reinterpret_cast<const float4*>(bta + 256 + lane * 4);
    float4 oa, ob;
    oa.x = (xa.x - mu) * rstd * ga.x + ba.x;
    oa.y = (xa.y - mu) * rstd * ga.y + ba.y;
    oa.z = (xa.z - mu) * rstd * ga.z + ba.z;
    oa.w = (xa.w - mu) * rstd * ga.w + ba.w;
    ob.x = (xb.x - mu) * rstd * gb.x + bb.x;
    ob.y = (xb.y - mu) * rstd * gb.y + bb.y;
    ob.z = (xb.z - mu) * rstd * gb.z + bb.z;
    ob.w = (xb.w - mu) * rstd * gb.w + bb.w;
    *reinterpret_cast<float4*>(h + base + lane * 4) = oa;
    *reinterpret_cast<float4*>(h + base + 256 + lane * 4) = ob;
}

// ------------------------- final projection (wave per token) -----------------
__global__ __launch_bounds__(256) void proj_k(
    const float* __restrict__ h, const float* __restrict__ pw,
    const float* __restrict__ pb, float* __restrict__ out)
{
    const int wid = (blockIdx.x * 256 + threadIdx.x) >> 6;  // 0..4095
    const int lane = threadIdx.x & 63;
    const int b = wid >> 9, tt = wid & 511;
    const float* row = h + (size_t)(b * 2048 + 1536 + tt) * 512;
    const float4 h0 = reinterpret_cast<const float4*>(row)[lane * 2];
    const float4 h1 = reinterpret_cast<const float4*>(row)[lane * 2 + 1];
    const float he[8] = {h0.x, h0.y, h0.z, h0.w, h1.x, h1.y, h1.z, h1.w};
    float acc[7] = {};
    #pragma unroll
    for (int e = 0; e < 8; ++e) {
        const int k = lane * 8 + e;
        #pragma unroll
        for (int cq = 0; cq < 7; ++cq) acc[cq] = fmaf(he[e], pw[k * 7 + cq], acc[cq]);
    }
    #pragma unroll
    for (int cq = 0; cq < 7; ++cq) {
        #pragma unroll
        for (int off = 32; off > 0; off >>= 1) acc[cq] += __shfl_xor(acc[cq], off);
    }
    if (lane == 0) {
        const size_t ob = ((size_t)(b * 512) + tt) * 7;
        #pragma unroll
        for (int cq = 0; cq < 7; ++cq) out[ob + cq] = acc[cq] + pb[cq];
    }
}

__global__ void nan_k(float* o) { o[0] = __int_as_float(0x7fc00000); }

// ---------------------------------------------------------------------------
extern "C" void kernel_launch(void* const* d_in, const int* in_sizes, int n_in,
                              void* d_out, int out_size, void* d_ws, size_t ws_size,
                              hipStream_t stream)
{
    const float* x_enc  = (const float*)d_in[0];
    const float* x_me   = (const float*)d_in[1];
    const float* x_dec  = (const float*)d_in[2];
    const float* x_md   = (const float*)d_in[3];
    const float* conv_w = (const float*)d_in[4];
    const float* time_w = (const float*)d_in[5];
    const float* qk_w   = (const float*)d_in[6];
    const float* v_w    = (const float*)d_in[7];
    const float* out_w  = (const float*)d_in[8];
    const float* out_b  = (const float*)d_in[9];
    const float* rots   = (const float*)d_in[10];
    const float* f1w    = (const float*)d_in[11];
    const float* f1b    = (const float*)d_in[12];
    const float* f2w    = (const float*)d_in[13];
    const float* f2b    = (const float*)d_in[14];
    const float* n1g    = (const float*)d_in[15];
    const float* n1b    = (const float*)d_in[16];
    const float* n2g    = (const float*)d_in[17];
    const float* n2b    = (const float*)d_in[18];
    const float* nfg    = (const float*)d_in[19];
    const float* nfb    = (const float*)d_in[20];
    const float* pw     = (const float*)d_in[21];
    const float* pb     = (const float*)d_in[22];

    // workspace layout (bytes) — identical to R3/R5/R6/R8/R9
    char* ws = (char*)d_ws;
    const size_t HBYT = (size_t)ROWS * DM * 4;                   // 33.5 MB
    float* h    = (float*)ws;                  ws += HBYT;
    unsigned short* hb = (unsigned short*)ws;  ws += HBYT / 2;   // bf16 h
    float* qkb  = (float*)ws;                  ws += HBYT;       // qk fp32; ab (bf16) aliases
    float* gout = (float*)ws;                  ws += HBYT;       // GEMM fp32 out; vbf aliases
    unsigned short* mid = (unsigned short*)ws; ws += (size_t)ROWS * DFF * 2; // 67MB, also 'so'
    float* slog = (float*)ws;                  ws += (size_t)BHN * SORTN * 4;
    int* buckets = (int*)ws;                   ws += (size_t)BHN * SORTN * 4;
    int* st_sorted = (int*)ws;                 ws += (size_t)BHN * SORTN * 4;
    int* pos_of = (int*)ws;                    ws += (size_t)BHN * SORTN * 4;
    unsigned short* wT = (unsigned short*)ws;  ws += (size_t)(2*262144 + 2*262144 + 2*1048576 + 2*1048576) * 2;
    const size_t need = (size_t)(ws - (char*)d_ws);
    if (ws_size < need) { nan_k<<<1, 1, 0, stream>>>((float*)d_out); return; }

    unsigned short* vT  = wT;                 // [l][512][512]
    unsigned short* oT  = vT + 2 * 262144;    // [l][512][512]
    unsigned short* f1T = oT + 2 * 262144;    // [l][2048][512]
    unsigned short* f2T = f1T + 2 * 1048576;  // [l][512][2048]
    unsigned short* ab  = (unsigned short*)qkb;   // bf16 attn output (aliases qk)
    unsigned short* vbf = (unsigned short*)gout;  // bf16 v (aliases gout)

    // weight transpose-casts (bf16, [N][K]); z = layer
    tcast_k<<<dim3(16, 16, 2), 256, 0, stream>>>(v_w,   vT,  DM, DM);
    tcast_k<<<dim3(16, 16, 2), 256, 0, stream>>>(out_w, oT,  DM, DM);
    tcast_k<<<dim3(16, 64, 2), 256, 0, stream>>>(f1w,   f1T, DM, DFF);
    tcast_k<<<dim3(64, 16, 2), 256, 0, stream>>>(f2w,   f2T, DFF, DM);

    embed_k<<<ROWS, 512, 0, stream>>>(x_enc, x_me, x_dec, x_md, conv_w, time_w, h, hb);

    for (int l = 0; l < 2; ++l) {
        const size_t wo = (size_t)l * DM * DM;
        // qk: fp32 (hash argmax is a discrete decision); v: bf16 MFMA
        gemm_k<<<dim3(ROWS/64, DM/64), 256, 0, stream>>>(h, qk_w + wo, qkb, ROWS, DM, DM);
        mgemm_k<1,0,0><<<dim3(ROWS/128, DM/128), 256, 0, stream>>>(hb, vT + (size_t)l*262144, nullptr, vbf, DM, DM);
        // LSH hash + stable sort
        hash_k<<<(NHASH * BHN * SEQL) / 256, 256, 0, stream>>>(qkb, rots + (size_t)l * DH * NHASH * (NBUCK/2), buckets);
        sort_k<<<BHN * 4, 256, 0, stream>>>(buckets, st_sorted, pos_of);
        // MFMA chunked attention (sorted order), unsort + combine
        lsh_attn_k<<<dim3(NCHUNK, BHN), 256, 0, stream>>>(qkb, vbf, st_sorted, mid /*so*/, slog);
        combine_k<<<(BHN * SEQL * DH) / 256, 256, 0, stream>>>(mid, slog, pos_of, ab);
        // output projection + residual LN
        mgemm_k<0,0,1><<<dim3(ROWS/128, DM/128), 256, 0, stream>>>(ab, oT + (size_t)l*262144, out_b + l * DM, gout, DM, DM);
        ln_k<1,1><<<ROWS/4, 256, 0, stream>>>(h, gout, n1g + l * DM, n1b + l * DM, hb);
        // FFN (bf16 MFMA)
        mgemm_k<1,1,1><<<dim3(ROWS/128, DFF/128), 256, 0, stream>>>(hb, f1T + (size_t)l*1048576, f1b + l * DFF, mid, DFF, DM);
        mgemm_k<0,0,1><<<dim3(ROWS/128, DM/128), 256, 0, stream>>>(mid, f2T + (size_t)l*1048576, f2b + l * DM, gout, DM, DFF);
        ln_k<1,1><<<ROWS/4, 256, 0, stream>>>(h, gout, n2g + l * DM, n2b + l * DM, hb);
    }
    lnf_k<<<(BATCH * 512) / 4, 256, 0, stream>>>(h, nfg, nfb);
    proj_k<<<(BATCH * 512 / 4), 256, 0, stream>>>(h, pw, pb, (float*)d_out);
}